// Round 1
// 806.564 us; speedup vs baseline: 1.5446x; 1.5446x over previous
//
#include <hip/hip_runtime.h>

// ---------------- problem constants ----------------
#define NPTS 100000
#define KNN  16

// workspace layout (float offsets)
#define Y_OFF    0            // y = x@w03+b03 : NPTS*64
#define BLWS_OFF 6400000      // symmetrized blW: 136 pairs x 16 o
#define C2AT_OFF 6402176      // c2a transposed+BN-folded: 64 x 32
#define T2A_OFF  6404224      // 64
#define C2BF_OFF 6404288      // c2b BN-folded: 64 x 8
#define T2B_OFF  6404800      // 8
#define AF_OFF   6404808      // linear_p folded 3x3
#define CF_OFF   6404817      // 3

// output layout (float offsets): (out, xk, knn_idx, p_r)
#define OUT_OFF  0
#define XK_OFF   6400000
#define IDXF_OFF 108800000
#define PR_OFF   110400000

#define EPSBN 1e-5f

// ---------------- prep: fold BNs, symmetrize blW ----------------
__global__ __launch_bounds__(256) void prep_small(
    const float* __restrict__ blW,
    const float* __restrict__ c2a_w, const float* __restrict__ g2a, const float* __restrict__ b2a,
    const float* __restrict__ m2a, const float* __restrict__ v2a,
    const float* __restrict__ c2b_w, const float* __restrict__ g2b, const float* __restrict__ b2b,
    const float* __restrict__ m2b, const float* __restrict__ v2b,
    const float* __restrict__ lp1_w, const float* __restrict__ lp1_b,
    const float* __restrict__ bnp_g, const float* __restrict__ bnp_b,
    const float* __restrict__ bnp_m, const float* __restrict__ bnp_v,
    float* __restrict__ ws)
{
    const int t = threadIdx.x;
    // symmetrized blW: pair (i<=j), value blW[o][i][j] (+ blW[o][j][i] if i<j)
    float* blWs = ws + BLWS_OFF;
    for (int u = t; u < 136 * 16; u += 256) {
        const int pidx = u >> 4, o = u & 15;
        int i = 0, rem = pidx;
        while (rem >= 16 - i) { rem -= 16 - i; i++; }
        const int j = i + rem;
        float v = blW[o * 256 + i * 16 + j];
        if (j > i) v += blW[o * 256 + j * 16 + i];
        blWs[pidx * 16 + o] = v;
    }
    float* c2aT = ws + C2AT_OFF;
    for (int u = t; u < 64 * 32; u += 256) {
        const int c = u >> 5, d = u & 31;
        const float f = g2a[c] / sqrtf(v2a[c] + EPSBN);
        c2aT[c * 32 + d] = c2a_w[d * 64 + c] * f;
    }
    if (t < 64) {
        const float f = g2a[t] / sqrtf(v2a[t] + EPSBN);
        (ws + T2A_OFF)[t] = b2a[t] - m2a[t] * f;
    }
    float* c2bf = ws + C2BF_OFF;
    for (int u = t; u < 64 * 8; u += 256) {
        const int s = u & 7;
        const float f = g2b[s] / sqrtf(v2b[s] + EPSBN);
        c2bf[u] = c2b_w[u] * f;
    }
    if (t < 8) {
        const float f = g2b[t] / sqrtf(v2b[t] + EPSBN);
        (ws + T2B_OFF)[t] = b2b[t] - m2b[t] * f;
    }
    if (t < 9) {
        const int j = t % 3;
        const float f = bnp_g[j] / sqrtf(bnp_v[j] + EPSBN);
        (ws + AF_OFF)[t] = lp1_w[t] * f;   // lp1_w[d*3+j] * f_j
    }
    if (t < 3) {
        const float f = bnp_g[t] / sqrtf(bnp_v[t] + EPSBN);
        (ws + CF_OFF)[t] = (lp1_b[t] - bnp_m[t]) * f + bnp_b[t];
    }
}

// ---------------- y = x @ w03 + b03  (one thread per (n, c4)) ----------------
__global__ __launch_bounds__(256) void y_gemm(
    const float* __restrict__ x, const float* __restrict__ w03,
    const float* __restrict__ b03, float* __restrict__ ws)
{
    const int tid = blockIdx.x * 256 + threadIdx.x;
    const int n = tid >> 4, c4 = tid & 15;
    const float4* __restrict__ x4 = (const float4*)x;
    const float4* __restrict__ w4 = (const float4*)w03;
    float4 acc = ((const float4*)b03)[c4];
    #pragma unroll 4
    for (int d4 = 0; d4 < 16; d4++) {
        const float4 xq = x4[n * 16 + d4];
        const float xs[4] = {xq.x, xq.y, xq.z, xq.w};
        #pragma unroll
        for (int e = 0; e < 4; e++) {
            const float4 wq = w4[(d4 * 4 + e) * 16 + c4];
            acc.x = fmaf(xs[e], wq.x, acc.x);
            acc.y = fmaf(xs[e], wq.y, acc.y);
            acc.z = fmaf(xs[e], wq.z, acc.z);
            acc.w = fmaf(xs[e], wq.w, acc.w);
        }
    }
    ((float4*)(ws + Y_OFF))[n * 16 + c4] = acc;
}

// ---------------- main fused kernel: one thread per (n,k) ----------------
__global__ __launch_bounds__(256) void pm_main(
    const float* __restrict__ p, const float* __restrict__ x,
    const int* __restrict__ knn,
    const float* __restrict__ w01, const float* __restrict__ b01,
    const float* __restrict__ blB,
    const float* __restrict__ lp2_w, const float* __restrict__ lp2_b,
    const float* __restrict__ c2c_w, const float* __restrict__ c2c_b,
    const float* __restrict__ ws, float* __restrict__ out)
{
    // per-thread metadata published for the coalesced phase-5 remap:
    // [0..3]=wgt[0..3], [4..7]=wgt[4..7], [8..10]=pe0..2, [11]=idx (bits)
    // row stride 12 floats (48B): 16B-aligned, bank-quad stride 3 (coprime 8)
    __shared__ float meta[256][12];

    const int tid = blockIdx.x * 256 + threadIdx.x;
    const int n = tid >> 4;
    const int k = tid & 15;
    const int idx = knn[tid];

    const float prx = p[idx * 3 + 0] - p[n * 3 + 0];
    const float pry = p[idx * 3 + 1] - p[n * 3 + 1];
    const float prz = p[idx * 3 + 2] - p[n * 3 + 2];
    out[IDXF_OFF + tid] = (float)idx;
    out[PR_OFF + tid * 3 + 0] = prx;
    out[PR_OFF + tid * 3 + 1] = pry;
    out[PR_OFF + tid * 3 + 2] = prz;

    // ---- phase 1: h = relu([p_r, x[idx]] @ w01 + b01) ----
    const float2* __restrict__ w01_2 = (const float2*)w01;
    float2 h2[8];
    {
        const float2* b01_2 = (const float2*)b01;
        #pragma unroll
        for (int t = 0; t < 8; t++) h2[t] = b01_2[t];
    }
    {
        const float pr3[3] = {prx, pry, prz};
        #pragma unroll
        for (int c = 0; c < 3; c++) {
            const float xv = pr3[c];
            #pragma unroll
            for (int t = 0; t < 8; t++) {
                const float2 w2 = w01_2[c * 8 + t];
                h2[t].x = fmaf(xv, w2.x, h2[t].x);
                h2[t].y = fmaf(xv, w2.y, h2[t].y);
            }
        }
    }
    {
        const float4* __restrict__ x4 = (const float4*)x;
        #pragma unroll 4
        for (int c4 = 0; c4 < 16; c4++) {
            const float4 xq = x4[idx * 16 + c4];
            const float xs[4] = {xq.x, xq.y, xq.z, xq.w};
            #pragma unroll
            for (int e = 0; e < 4; e++) {
                const float xv = xs[e];
                const int cc = 3 + c4 * 4 + e;
                #pragma unroll
                for (int t = 0; t < 8; t++) {
                    const float2 w2 = w01_2[cc * 8 + t];
                    h2[t].x = fmaf(xv, w2.x, h2[t].x);
                    h2[t].y = fmaf(xv, w2.y, h2[t].y);
                }
            }
        }
    }
    float h[16];
    #pragma unroll
    for (int t = 0; t < 8; t++) {
        h[2 * t]     = fmaxf(h2[t].x, 0.f);
        h[2 * t + 1] = fmaxf(h2[t].y, 0.f);
    }

    // ---- phase 2: energy[o] = sum_{i<=j} hs_ij * blWs[(i,j)][o] + blB ----
    float2 e2[8];
    {
        const float2* blB2 = (const float2*)blB;
        #pragma unroll
        for (int t = 0; t < 8; t++) e2[t] = blB2[t];
    }
    {
        const float2* __restrict__ blWs2 = (const float2*)(ws + BLWS_OFF);
        int pidx = 0;
        #pragma unroll
        for (int i = 0; i < 16; i++) {
            #pragma unroll
            for (int j = i; j < 16; j++) {
                const float u = h[i] * h[j];
                const float2* wr = blWs2 + pidx * 8;
                #pragma unroll
                for (int t = 0; t < 8; t++) {
                    const float2 w2 = wr[t];
                    e2[t].x = fmaf(u, w2.x, e2[t].x);
                    e2[t].y = fmaf(u, w2.y, e2[t].y);
                }
                pidx++;
            }
        }
    }

    // ---- phase 3: pe = relu(BN(p_r@lp1)+..) folded; shrink from rank-1 p_embed ----
    float pe0, pe1, pe2;
    {
        const float* Af = ws + AF_OFF;
        const float* cf = ws + CF_OFF;
        pe0 = fmaxf(fmaf(prx, Af[0], fmaf(pry, Af[3], fmaf(prz, Af[6], cf[0]))), 0.f);
        pe1 = fmaxf(fmaf(prx, Af[1], fmaf(pry, Af[4], fmaf(prz, Af[7], cf[1]))), 0.f);
        pe2 = fmaxf(fmaf(prx, Af[2], fmaf(pry, Af[5], fmaf(prz, Af[8], cf[2]))), 0.f);
    }
    float2 sh2[8];
    #pragma unroll
    for (int t = 0; t < 8; t++) {
        float s0 = 0.f, s1 = 0.f;
        #pragma unroll
        for (int a = 0; a < 4; a++) {
            const int c0 = a * 16 + 2 * t;
            s0 += fmaf(pe0, lp2_w[c0],     fmaf(pe1, lp2_w[64 + c0],     fmaf(pe2, lp2_w[128 + c0],     lp2_b[c0])));
            s1 += fmaf(pe0, lp2_w[c0 + 1], fmaf(pe1, lp2_w[64 + c0 + 1], fmaf(pe2, lp2_w[128 + c0 + 1], lp2_b[c0 + 1])));
        }
        sh2[t] = make_float2(s0, s1);
    }

    // ---- phase 4: c2a(BN,relu) -> c2b(BN,relu) -> c2c -> softmax over k ----
    float2 s2[4];
    {
        const float2* t2b2 = (const float2*)(ws + T2B_OFF);
        #pragma unroll
        for (int t = 0; t < 4; t++) s2[t] = t2b2[t];
    }
    {
        const float2* __restrict__ c2aT2 = (const float2*)(ws + C2AT_OFF);
        const float2* __restrict__ c2bf2 = (const float2*)(ws + C2BF_OFF);
        const float* __restrict__ t2a = ws + T2A_OFF;
        #pragma unroll 2
        for (int c = 0; c < 64; c++) {
            const float2* wr = c2aT2 + c * 16;
            float ax = 0.f, ay = 0.f;
            #pragma unroll
            for (int t = 0; t < 8; t++) {
                const float2 w2 = wr[t];
                ax = fmaf(e2[t].x, w2.x, ax);
                ay = fmaf(e2[t].y, w2.y, ay);
            }
            #pragma unroll
            for (int t = 0; t < 8; t++) {
                const float2 w2 = wr[8 + t];
                ax = fmaf(sh2[t].x, w2.x, ax);
                ay = fmaf(sh2[t].y, w2.y, ay);
            }
            const float hc = fmaxf(ax + ay + t2a[c], 0.f);
            const float2* br = c2bf2 + c * 4;
            #pragma unroll
            for (int t = 0; t < 4; t++) {
                const float2 w2 = br[t];
                s2[t].x = fmaf(hc, w2.x, s2[t].x);
                s2[t].y = fmaf(hc, w2.y, s2[t].y);
            }
        }
    }
    float h2b[8];
    #pragma unroll
    for (int t = 0; t < 4; t++) {
        h2b[2 * t]     = fmaxf(s2[t].x, 0.f);
        h2b[2 * t + 1] = fmaxf(s2[t].y, 0.f);
    }
    float2 l2[4];
    {
        const float2* cb2 = (const float2*)c2c_b;
        #pragma unroll
        for (int t = 0; t < 4; t++) l2[t] = cb2[t];
        const float2* c2c2 = (const float2*)c2c_w;
        #pragma unroll
        for (int s = 0; s < 8; s++) {
            const float hv = h2b[s];
            #pragma unroll
            for (int t = 0; t < 4; t++) {
                const float2 w2 = c2c2[s * 4 + t];
                l2[t].x = fmaf(hv, w2.x, l2[t].x);
                l2[t].y = fmaf(hv, w2.y, l2[t].y);
            }
        }
    }
    float wgt[8];
    #pragma unroll
    for (int s = 0; s < 8; s++) {
        const float l = (s & 1) ? l2[s >> 1].y : l2[s >> 1].x;
        float m = l;
        m = fmaxf(m, __shfl_xor(m, 1, 64));
        m = fmaxf(m, __shfl_xor(m, 2, 64));
        m = fmaxf(m, __shfl_xor(m, 4, 64));
        m = fmaxf(m, __shfl_xor(m, 8, 64));
        const float ex = __expf(l - m);
        float sm = ex;
        sm += __shfl_xor(sm, 1, 64);
        sm += __shfl_xor(sm, 2, 64);
        sm += __shfl_xor(sm, 4, 64);
        sm += __shfl_xor(sm, 8, 64);
        wgt[s] = ex / sm;
    }

    // ---- phase 4.5: publish per-(n,k) state to LDS ----
    {
        float4* m4 = (float4*)&meta[threadIdx.x][0];
        m4[0] = make_float4(wgt[0], wgt[1], wgt[2], wgt[3]);
        m4[1] = make_float4(wgt[4], wgt[5], wgt[6], wgt[7]);
        m4[2] = make_float4(pe0, pe1, pe2, __int_as_float(idx));
    }
    __syncthreads();

    // ---- phase 5 (remapped): lane l owns (k = j*4 + l>>4, c4 = l&15) for each
    // of its wave's 4 points. xk stores are 1KB-contiguous per instruction;
    // y rows are read by 16 contiguous lanes (full-line coalesced). ----
    {
        const int lane = threadIdx.x & 63;
        const int waveBase = threadIdx.x & 192;      // wave's first thread in block
        const int c4 = lane & 15;                    // channel quad owned by lane
        const int kh = lane >> 4;                    // k sub-index
        // lp2 columns for this lane's 4 channels c = c4*4 + e
        const float4 lw0 = ((const float4*)lp2_w)[c4];
        const float4 lw1 = ((const float4*)lp2_w)[16 + c4];
        const float4 lw2 = ((const float4*)lp2_w)[32 + c4];
        const float4 lb  = ((const float4*)lp2_b)[c4];
        const float4* __restrict__ y4 = (const float4*)(ws + Y_OFF);
        const int nBase = blockIdx.x * 16 + (waveBase >> 4);
        const int wsel = c4 & 1;                     // wgt[c&7] quad: (c4&1)*4 + e
        for (int g = 0; g < 4; g++) {
            const int n_g = nBase + g;
            float4 racc = make_float4(0.f, 0.f, 0.f, 0.f);
            #pragma unroll
            for (int j = 0; j < 4; j++) {
                const int s = waveBase + g * 16 + j * 4 + kh;   // source thread (n_g, k)
                const float4 wv = *((const float4*)&meta[s][0] + wsel);
                const float4 pv = *((const float4*)&meta[s][0] + 2);
                const int sidx = __float_as_int(pv.w);
                const float4 yv = y4[sidx * 16 + c4];
                float4 r;
                r.x = (yv.x + fmaf(pv.x, lw0.x, fmaf(pv.y, lw1.x, fmaf(pv.z, lw2.x, lb.x)))) * wv.x;
                r.y = (yv.y + fmaf(pv.x, lw0.y, fmaf(pv.y, lw1.y, fmaf(pv.z, lw2.y, lb.y)))) * wv.y;
                r.z = (yv.z + fmaf(pv.x, lw0.z, fmaf(pv.y, lw1.z, fmaf(pv.z, lw2.z, lb.z)))) * wv.z;
                r.w = (yv.w + fmaf(pv.x, lw0.w, fmaf(pv.y, lw1.w, fmaf(pv.z, lw2.w, lb.w)))) * wv.w;
                *((float4*)(out + XK_OFF + n_g * 1024 + (j * 64 + lane) * 4)) = r;
                racc.x += r.x; racc.y += r.y; racc.z += r.z; racc.w += r.w;
            }
            // reduce over kh groups (k blocks) -> full sum over k
            racc.x += __shfl_xor(racc.x, 16, 64); racc.y += __shfl_xor(racc.y, 16, 64);
            racc.z += __shfl_xor(racc.z, 16, 64); racc.w += __shfl_xor(racc.w, 16, 64);
            racc.x += __shfl_xor(racc.x, 32, 64); racc.y += __shfl_xor(racc.y, 32, 64);
            racc.z += __shfl_xor(racc.z, 32, 64); racc.w += __shfl_xor(racc.w, 32, 64);
            if (kh == 0)
                *((float4*)(out + OUT_OFF + n_g * 64 + c4 * 4)) = racc;
        }
    }
}

// ---------------- launch ----------------
extern "C" void kernel_launch(void* const* d_in, const int* in_sizes, int n_in,
                              void* d_out, int out_size, void* d_ws, size_t ws_size,
                              hipStream_t stream) {
    const float* p     = (const float*)d_in[0];
    const float* x     = (const float*)d_in[1];
    const int*   knn   = (const int*)d_in[2];
    const float* w01   = (const float*)d_in[3];
    const float* b01   = (const float*)d_in[4];
    const float* blW   = (const float*)d_in[5];
    const float* blB   = (const float*)d_in[6];
    const float* lp1_w = (const float*)d_in[7];
    const float* lp1_b = (const float*)d_in[8];
    const float* bnp_g = (const float*)d_in[9];
    const float* bnp_b = (const float*)d_in[10];
    const float* bnp_m = (const float*)d_in[11];
    const float* bnp_v = (const float*)d_in[12];
    const float* lp2_w = (const float*)d_in[13];
    const float* lp2_b = (const float*)d_in[14];
    const float* c2a_w = (const float*)d_in[15];
    const float* g2a   = (const float*)d_in[16];
    const float* b2a   = (const float*)d_in[17];
    const float* m2a   = (const float*)d_in[18];
    const float* v2a   = (const float*)d_in[19];
    const float* c2b_w = (const float*)d_in[20];
    const float* g2b   = (const float*)d_in[21];
    const float* b2b   = (const float*)d_in[22];
    const float* m2b   = (const float*)d_in[23];
    const float* v2b   = (const float*)d_in[24];
    const float* c2c_w = (const float*)d_in[25];
    const float* c2c_b = (const float*)d_in[26];
    const float* w03   = (const float*)d_in[27];
    const float* b03   = (const float*)d_in[28];
    float* ws  = (float*)d_ws;
    float* out = (float*)d_out;

    prep_small<<<1, 256, 0, stream>>>(blW, c2a_w, g2a, b2a, m2a, v2a,
                                      c2b_w, g2b, b2b, m2b, v2b,
                                      lp1_w, lp1_b, bnp_g, bnp_b, bnp_m, bnp_v, ws);
    y_gemm<<<(NPTS * 16) / 256, 256, 0, stream>>>(x, w03, b03, ws);
    pm_main<<<(NPTS * KNN) / 256, 256, 0, stream>>>(p, x, knn, w01, b01, blB,
                                                    lp2_w, lp2_b, c2c_w, c2c_b, ws, out);
}